// Round 9
// baseline (658.677 us; speedup 1.0000x reference)
//
#include <hip/hip_runtime.h>

#define NTHREADS 512

typedef __attribute__((ext_vector_type(8))) short s16x8;
typedef __attribute__((ext_vector_type(4))) float f32x4;
typedef __attribute__((ext_vector_type(4))) unsigned int u32x4;

__device__ __forceinline__ unsigned short f2bf(float f) {
  unsigned u = __float_as_uint(f);
  u += 0x7fffu + ((u >> 16) & 1u);
  return (unsigned short)(u >> 16);
}
__device__ __forceinline__ float bf2f(unsigned short s) {
  return __uint_as_float(((unsigned)s) << 16);
}
__device__ __forceinline__ float sigm(float x) {
  return __builtin_amdgcn_rcpf(1.0f + __expf(-x));
}
__device__ __forceinline__ float tanh_fast(float x) {
  return 1.0f - 2.0f * __builtin_amdgcn_rcpf(1.0f + __expf(2.0f * x));
}
__device__ __forceinline__ f32x4 mfma_bf16(u32x4 a, u32x4 b, f32x4 c) {
  union { u32x4 u; s16x8 s; } ua, ub;
  ua.u = a; ub.u = b;
  return __builtin_amdgcn_mfma_f32_16x16x32_bf16(ua.s, ub.s, c, 0, 0, 0);
}
// persistent c-state parked in the acc half of the unified file.
// MUST be indexed with compile-time constants: round 8 ran the jt loop
// rolled -> runtime index -> the c arrays were lowered to scratch
// (335 MB/dispatch of scratch r+w, measured as WRITE_SIZE 359 MB).
__device__ __forceinline__ float agpr_st(float v) {
  float r;
  asm("v_accvgpr_write_b32 %0, %1" : "=a"(r) : "v"(v));
  return r;
}
__device__ __forceinline__ float agpr_ld(float a) {
  float r;
  asm("v_accvgpr_read_b32 %0, %1" : "=v"(r) : "a"(a));
  return r;
}

// ---------------- weight pre-pack ----------------
// Layout (rolled-loop friendly): [nb(16)][kb][g(4)][16 n][8 k], bf16.
//   W0p: kb in [0,52)  (k = kb*8: k<160 from W_ih0, else W_hh0)
//   W1p: kb in [0,64)  (k<256 from W_ih1, else W_hh1)
// Per k-group a wave advances ONE pointer by 4096 B; the 4 gate fragments
// are imm offsets 0/256/512/768 B. b0/b1: b_ih+b_hh pre-summed, f32.
__global__ void pack_weights(const float* __restrict__ Wih0, const float* __restrict__ Whh0,
                             const float* __restrict__ bih0, const float* __restrict__ bhh0,
                             const float* __restrict__ Wih1, const float* __restrict__ Whh1,
                             const float* __restrict__ bih1, const float* __restrict__ bhh1,
                             unsigned short* __restrict__ W0p, unsigned short* __restrict__ W1p,
                             float* __restrict__ b0, float* __restrict__ b1) {
  int e = blockIdx.x * 256 + threadIdx.x;
  const int N0 = 16 * 52 * 4 * 128;   // 425984
  const int N1 = 16 * 64 * 4 * 128;   // 524288
  if (e < N0) {
    int kk = e & 7, t1 = e >> 3;
    int n = t1 & 15, t2 = t1 >> 4;
    int g = t2 & 3, t3 = t2 >> 2;
    int kb = t3 % 52, nb = t3 / 52;
    int gn = g * 256 + nb * 16 + n, k = kb * 8 + kk;
    float v = (k < 160) ? Wih0[gn * 160 + k] : Whh0[gn * 256 + (k - 160)];
    W0p[e] = f2bf(v);
  } else if (e < N0 + N1) {
    int e2 = e - N0;
    int kk = e2 & 7, t1 = e2 >> 3;
    int n = t1 & 15, t2 = t1 >> 4;
    int g = t2 & 3, t3 = t2 >> 2;
    int kb = t3 & 63, nb = t3 >> 6;
    int gn = g * 256 + nb * 16 + n, k = kb * 8 + kk;
    float v = (k < 256) ? Wih1[gn * 256 + k] : Whh1[gn * 256 + (k - 256)];
    W1p[e2] = f2bf(v);
  } else if (e < N0 + N1 + 1024) {
    int n = e - (N0 + N1);
    b0[n] = bih0[n] + bhh0[n];
  } else if (e < N0 + N1 + 2048) {
    int n = e - (N0 + N1 + 1024);
    b1[n] = bih1[n] + bhh1[n];
  }
}

// ---- rolled, software-pipelined K-loop (N k-groups of 32) ----
// A and B fragment loads share one shape: p[0],p[16],p[32],p[48]
// (imm offsets 0/256/512/768 B), pointer stride 256 u32x4 = 4096 B/group.
// Static 2-slot double buffer; #pragma unroll 1 keeps the body small
// (rounds 1-7: fully-unrolled K-loops -> ~20 KB bodies, chronic spills,
// all pipes <10%; rolling them was the 1616->483 us win of round 8).
__device__ __forceinline__ void ld4(u32x4 d[4], const u32x4* p) {
  d[0] = p[0]; d[1] = p[16]; d[2] = p[32]; d[3] = p[48];
}
__device__ __forceinline__ void mfma16(const u32x4 a[4], const u32x4 b[4],
                                       f32x4 acc[4][4]) {
#pragma unroll
  for (int g = 0; g < 4; g++)
#pragma unroll
    for (int rt = 0; rt < 4; rt++)
      acc[g][rt] = mfma_bf16(a[rt], b[g], acc[g][rt]);
}
template <int N>
__device__ __forceinline__ void kloop(const u32x4*& ap, const u32x4*& wp,
                                      f32x4 acc[4][4]) {
  u32x4 a0[4], b0[4], a1[4], b1[4];
  ld4(a0, ap); ld4(b0, wp); ap += 256; wp += 256;
#pragma unroll 1
  for (int i = 0; i < (N - 1) / 2; i++) {
    ld4(a1, ap); ld4(b1, wp); ap += 256; wp += 256;
    mfma16(a0, b0, acc);
    ld4(a0, ap); ld4(b0, wp); ap += 256; wp += 256;
    mfma16(a1, b1, acc);
  }
  if constexpr ((N & 1) == 0) {
    ld4(a1, ap); ld4(b1, wp); ap += 256; wp += 256;
    mfma16(a0, b0, acc);
    mfma16(a1, b1, acc);
  } else {
    mfma16(a0, b0, acc);
  }
}

// ---------------- fused 2-layer LSTM + FC ----------------
// 256 blocks x 512 threads; block owns 64 batch rows for all 10 steps.
// LDS 158 KB (1 blk/CU, 2 waves/SIMD): x-tile + double-buffered h1/h2 in
// bf16 A-layout [kblk][row][8k] + biases; 3 barriers/step.
// K-loops rolled; jt loop UNROLLED (x2) so c0a/c2a keep static indices
// and stay in AGPRs (round 8's rolled jt put them in scratch: 359 MB).
__global__ __attribute__((amdgpu_flat_work_group_size(NTHREADS, NTHREADS),
                          amdgpu_waves_per_eu(2, 2)))
void lstm_fused(const float* __restrict__ x,
                const unsigned short* __restrict__ W0p,
                const unsigned short* __restrict__ W1p,
                const float* __restrict__ b0,
                const float* __restrict__ b1,
                const float* __restrict__ Wfc,
                const float* __restrict__ bfc,
                float* __restrict__ out) {
  __shared__ unsigned int lds_x[20 * 64 * 4];   // 20480 B
  __shared__ unsigned int lds_h1[16384];        // 65536 B = 2 bufs x [32 kblk][64 row][8k]
  __shared__ unsigned int lds_h2[16384];        // 65536 B
  __shared__ float lds_red[512];                // 2048 B
  __shared__ float lds_b0[1024];                // 4096 B
  __shared__ float lds_b1[1024];                // 4096 B   total 161792 B

  const int tid = threadIdx.x;
  const int wave = tid >> 6;
  const int lane = tid & 63;
  const int l15 = lane & 15;
  const int quad = lane >> 4;
  const long rowg0 = (long)blockIdx.x * 64;

  for (int i = tid; i < 16384; i += NTHREADS) { lds_h1[i] = 0u; lds_h2[i] = 0u; }
  for (int i = tid; i < 1024; i += NTHREADS) { lds_b0[i] = b0[i]; lds_b1[i] = b1[i]; }

  // persistent c-state pinned to AGPRs (static indices only!)
  float c0a[2][4][4], c2a[2][4][4];
#pragma unroll
  for (int jt = 0; jt < 2; jt++)
#pragma unroll
    for (int rt = 0; rt < 4; rt++)
#pragma unroll
      for (int r = 0; r < 4; r++) {
        c0a[jt][rt][r] = agpr_st(0.f);
        c2a[jt][rt][r] = agpr_st(0.f);
      }
  float fc_acc = 0.0f;

  const u32x4* lxs = (const u32x4*)lds_x;
  const u32x4* lh1 = (const u32x4*)lds_h1;
  const u32x4* lh2 = (const u32x4*)lds_h2;
  unsigned short* lh1s = (unsigned short*)lds_h1;
  unsigned short* lh2s = (unsigned short*)lds_h2;
  const u32x4* w0q = (const u32x4*)W0p;
  const u32x4* w1q = (const u32x4*)W1p;

  for (int t = 0; t < 10; t++) {
    const int rd = t & 1;        // prev-h buffer
    const int wr = rd ^ 1;       // new-h buffer

    // ---- stage x_t -> lds_x (bf16 A-layout) ----
#pragma unroll
    for (int s = 0; s < 5; s++) {
      int p = tid + s * NTHREADS;          // 2560 f32x4 = 64 rows x 40 quads
      int row = p / 40;
      int kq = p - row * 40;
      const f32x4 v = __builtin_nontemporal_load(
          (const f32x4*)(x + (rowg0 + row) * 1600 + t * 160 + kq * 4));
      unsigned lo = (unsigned)f2bf(v[0]) | ((unsigned)f2bf(v[1]) << 16);
      unsigned hi = (unsigned)f2bf(v[2]) | ((unsigned)f2bf(v[3]) << 16);
      int base = (kq >> 1) * 256 + row * 4 + (kq & 1) * 2;
      lds_x[base] = lo;
      lds_x[base + 1] = hi;
    }
    __syncthreads();  // B1: x staged; h1[rd] stable from prev step

    // ======== layer 0: K=416 ([x_t | h1_prev]) ========
#pragma unroll
    for (int jt = 0; jt < 2; jt++) {
      const int nbb = wave * 2 + jt;
      f32x4 acc[4][4];
#pragma unroll
      for (int g = 0; g < 4; g++)
#pragma unroll
        for (int rt = 0; rt < 4; rt++) acc[g][rt] = (f32x4){0.f, 0.f, 0.f, 0.f};

      const u32x4* wp = w0q + (nbb * 52 + quad) * 64 + l15;
      const u32x4* ap = lxs + quad * 64 + l15;
      kloop<5>(ap, wp, acc);                       // x-part: k 0..159
      ap = lh1 + rd * 2048 + quad * 64 + l15;
      kloop<8>(ap, wp, acc);                       // h-part: k 160..415

      float b_i = lds_b0[0 * 256 + wave * 32 + jt * 16 + l15];
      float b_f = lds_b0[1 * 256 + wave * 32 + jt * 16 + l15];
      float b_g = lds_b0[2 * 256 + wave * 32 + jt * 16 + l15];
      float b_o = lds_b0[3 * 256 + wave * 32 + jt * 16 + l15];
#pragma unroll
      for (int rt = 0; rt < 4; rt++)
#pragma unroll
        for (int r = 0; r < 4; r++) {
          float iv = sigm(acc[0][rt][r] + b_i);
          float fv = sigm(acc[1][rt][r] + b_f);
          float gv = tanh_fast(acc[2][rt][r] + b_g);
          float ov = sigm(acc[3][rt][r] + b_o);
          float cn = fv * agpr_ld(c0a[jt][rt][r]) + iv * gv;
          c0a[jt][rt][r] = agpr_st(cn);
          int row = rt * 16 + quad * 4 + r;
          int col = wave * 32 + jt * 16 + l15;
          lh1s[wr * 16384 + ((col >> 3) * 64 + row) * 8 + (col & 7)] =
              f2bf(ov * tanh_fast(cn));
        }
    }
    __syncthreads();  // B2: h1[wr] complete

    // ======== layer 1: K=512 ([h1_new | h2_prev]) ========
#pragma unroll
    for (int jt = 0; jt < 2; jt++) {
      const int nbb = wave * 2 + jt;
      f32x4 acc[4][4];
#pragma unroll
      for (int g = 0; g < 4; g++)
#pragma unroll
        for (int rt = 0; rt < 4; rt++) acc[g][rt] = (f32x4){0.f, 0.f, 0.f, 0.f};

      const u32x4* wp = w1q + (nbb * 64 + quad) * 64 + l15;
      const u32x4* ap = lh1 + wr * 2048 + quad * 64 + l15;
      kloop<8>(ap, wp, acc);                       // h1_new part: k 0..255
      ap = lh2 + rd * 2048 + quad * 64 + l15;
      kloop<8>(ap, wp, acc);                       // h2_prev part: k 256..511

      float b_i = lds_b1[0 * 256 + wave * 32 + jt * 16 + l15];
      float b_f = lds_b1[1 * 256 + wave * 32 + jt * 16 + l15];
      float b_g = lds_b1[2 * 256 + wave * 32 + jt * 16 + l15];
      float b_o = lds_b1[3 * 256 + wave * 32 + jt * 16 + l15];
#pragma unroll
      for (int rt = 0; rt < 4; rt++)
#pragma unroll
        for (int r = 0; r < 4; r++) {
          float iv = sigm(acc[0][rt][r] + b_i);
          float fv = sigm(acc[1][rt][r] + b_f);
          float gv = tanh_fast(acc[2][rt][r] + b_g);
          float ov = sigm(acc[3][rt][r] + b_o);
          float cn = fv * agpr_ld(c2a[jt][rt][r]) + iv * gv;
          c2a[jt][rt][r] = agpr_st(cn);
          int row = rt * 16 + quad * 4 + r;
          int col = wave * 32 + jt * 16 + l15;
          lh2s[wr * 16384 + ((col >> 3) * 64 + row) * 8 + (col & 7)] =
              f2bf(ov * tanh_fast(cn));
        }
    }
    __syncthreads();  // B3: h2[wr] complete

    // ---- FC partial: logit += W_fc[t*256 + j] * h2_new[row][j] ----
    {
      int row = tid >> 3;
      int jq = (tid & 7) * 32;
      float s = 0.f;
#pragma unroll
      for (int kb = 0; kb < 4; kb++) {
        u32x4 hv = lh2[wr * 2048 + ((jq >> 3) + kb) * 64 + row];
        const f32x4 wA = *(const f32x4*)(Wfc + t * 256 + jq + kb * 8);
        const f32x4 wB = *(const f32x4*)(Wfc + t * 256 + jq + kb * 8 + 4);
#pragma unroll
        for (int e = 0; e < 2; e++) {
          unsigned u = hv[e];
          s += bf2f((unsigned short)(u & 0xffffu)) * wA[2 * e];
          s += bf2f((unsigned short)(u >> 16)) * wA[2 * e + 1];
        }
#pragma unroll
        for (int e = 0; e < 2; e++) {
          unsigned u = hv[2 + e];
          s += bf2f((unsigned short)(u & 0xffffu)) * wB[2 * e];
          s += bf2f((unsigned short)(u >> 16)) * wB[2 * e + 1];
        }
      }
      fc_acc += s;
    }
    // no barrier: next staging touches lds_x only; dbuf protects h regions.
  }

  lds_red[tid] = fc_acc;  // [row(64)][slot(8)]
  __syncthreads();
  if (tid < 64) {
    float s = 0.f;
#pragma unroll
    for (int e = 0; e < 8; e++) s += lds_red[tid * 8 + e];
    out[rowg0 + tid] = sigm(s + bfc[0]);
  }
}

extern "C" void kernel_launch(void* const* d_in, const int* in_sizes, int n_in,
                              void* d_out, int out_size, void* d_ws, size_t ws_size,
                              hipStream_t stream) {
  const float* x    = (const float*)d_in[0];
  const float* Wih0 = (const float*)d_in[1];
  const float* Whh0 = (const float*)d_in[2];
  const float* bih0 = (const float*)d_in[3];
  const float* bhh0 = (const float*)d_in[4];
  const float* Wih1 = (const float*)d_in[5];
  const float* Whh1 = (const float*)d_in[6];
  const float* bih1 = (const float*)d_in[7];
  const float* bhh1 = (const float*)d_in[8];
  const float* Wfc  = (const float*)d_in[9];
  const float* bfc  = (const float*)d_in[10];
  float* out = (float*)d_out;

  unsigned short* W0p = (unsigned short*)d_ws;         // 425984 bf16
  unsigned short* W1p = W0p + 16 * 52 * 4 * 128;       // 524288 bf16
  float* b0 = (float*)(W1p + 16 * 64 * 4 * 128);       // 1024 f32
  float* b1 = b0 + 1024;                               // 1024 f32

  const int total = 16 * 52 * 4 * 128 + 16 * 64 * 4 * 128 + 2048;
  pack_weights<<<(total + 255) / 256, 256, 0, stream>>>(
      Wih0, Whh0, bih0, bhh0, Wih1, Whh1, bih1, bhh1, W0p, W1p, b0, b1);
  lstm_fused<<<256, NTHREADS, 0, stream>>>(x, W0p, W1p, b0, b1, Wfc, bfc, out);
}

// Round 10
// 653.562 us; speedup vs baseline: 1.0078x; 1.0078x over previous
//
#include <hip/hip_runtime.h>

#define NTHREADS 512

typedef __attribute__((ext_vector_type(8))) short s16x8;
typedef __attribute__((ext_vector_type(4))) float f32x4;
typedef __attribute__((ext_vector_type(4))) unsigned int u32x4;

__device__ __forceinline__ unsigned short f2bf(float f) {
  unsigned u = __float_as_uint(f);
  u += 0x7fffu + ((u >> 16) & 1u);
  return (unsigned short)(u >> 16);
}
__device__ __forceinline__ float bf2f(unsigned short s) {
  return __uint_as_float(((unsigned)s) << 16);
}
// Gate math on raw v_exp_f32 (2^x) + v_rcp_f32: 4-5 VALU per gate.
// Round 9 PMC: VALU busy ~200us vs ~35us modeled -> __expf was expanding
// to the precise ocml exp (~20 instr). exp2-based forms cut it ~5x.
#define LOG2E 1.4426950408889634f
__device__ __forceinline__ float sigm(float x) {
  return __builtin_amdgcn_rcpf(1.0f + __builtin_amdgcn_exp2f(-LOG2E * x));
}
__device__ __forceinline__ float tanh_fast(float x) {
  return 1.0f - 2.0f * __builtin_amdgcn_rcpf(
                           1.0f + __builtin_amdgcn_exp2f((2.0f * LOG2E) * x));
}
__device__ __forceinline__ f32x4 mfma_bf16(u32x4 a, u32x4 b, f32x4 c) {
  union { u32x4 u; s16x8 s; } ua, ub;
  ua.u = a; ub.u = b;
  return __builtin_amdgcn_mfma_f32_16x16x32_bf16(ua.s, ub.s, c, 0, 0, 0);
}
// persistent c-state parked in the acc half of the unified file.
// MUST be indexed with compile-time constants (round 8: runtime jt index
// lowered the c arrays to scratch -> 335 MB/dispatch of scratch traffic).
__device__ __forceinline__ float agpr_st(float v) {
  float r;
  asm("v_accvgpr_write_b32 %0, %1" : "=a"(r) : "v"(v));
  return r;
}
__device__ __forceinline__ float agpr_ld(float a) {
  float r;
  asm("v_accvgpr_read_b32 %0, %1" : "=v"(r) : "a"(a));
  return r;
}

// ---------------- weight pre-pack ----------------
// Layout (rolled-loop friendly): [nb(16)][kb][g(4)][16 n][8 k], bf16.
//   W0p: kb in [0,52)  (k = kb*8: k<160 from W_ih0, else W_hh0)
//   W1p: kb in [0,64)  (k<256 from W_ih1, else W_hh1)
// Per k-group a wave advances ONE pointer by 4096 B; the 4 gate fragments
// are imm offsets 0/256/512/768 B. b0/b1: b_ih+b_hh pre-summed, f32.
__global__ void pack_weights(const float* __restrict__ Wih0, const float* __restrict__ Whh0,
                             const float* __restrict__ bih0, const float* __restrict__ bhh0,
                             const float* __restrict__ Wih1, const float* __restrict__ Whh1,
                             const float* __restrict__ bih1, const float* __restrict__ bhh1,
                             unsigned short* __restrict__ W0p, unsigned short* __restrict__ W1p,
                             float* __restrict__ b0, float* __restrict__ b1) {
  int e = blockIdx.x * 256 + threadIdx.x;
  const int N0 = 16 * 52 * 4 * 128;   // 425984
  const int N1 = 16 * 64 * 4 * 128;   // 524288
  if (e < N0) {
    int kk = e & 7, t1 = e >> 3;
    int n = t1 & 15, t2 = t1 >> 4;
    int g = t2 & 3, t3 = t2 >> 2;
    int kb = t3 % 52, nb = t3 / 52;
    int gn = g * 256 + nb * 16 + n, k = kb * 8 + kk;
    float v = (k < 160) ? Wih0[gn * 160 + k] : Whh0[gn * 256 + (k - 160)];
    W0p[e] = f2bf(v);
  } else if (e < N0 + N1) {
    int e2 = e - N0;
    int kk = e2 & 7, t1 = e2 >> 3;
    int n = t1 & 15, t2 = t1 >> 4;
    int g = t2 & 3, t3 = t2 >> 2;
    int kb = t3 & 63, nb = t3 >> 6;
    int gn = g * 256 + nb * 16 + n, k = kb * 8 + kk;
    float v = (k < 256) ? Wih1[gn * 256 + k] : Whh1[gn * 256 + (k - 256)];
    W1p[e2] = f2bf(v);
  } else if (e < N0 + N1 + 1024) {
    int n = e - (N0 + N1);
    b0[n] = bih0[n] + bhh0[n];
  } else if (e < N0 + N1 + 2048) {
    int n = e - (N0 + N1 + 1024);
    b1[n] = bih1[n] + bhh1[n];
  }
}

// ---- rolled, software-pipelined K-loop (N k-groups of 32) ----
// A and B fragment loads share one shape: p[0],p[16],p[32],p[48]
// (imm offsets 0/256/512/768 B), pointer stride 256 u32x4 = 4096 B/group.
// Static 2-slot double buffer; #pragma unroll 1 keeps the body small
// (rounds 1-7: fully-unrolled K-loops -> ~20 KB bodies, chronic spills,
// all pipes <10%; rolling them was the 1616->483 us win of round 8).
__device__ __forceinline__ void ld4(u32x4 d[4], const u32x4* p) {
  d[0] = p[0]; d[1] = p[16]; d[2] = p[32]; d[3] = p[48];
}
__device__ __forceinline__ void mfma16(const u32x4 a[4], const u32x4 b[4],
                                       f32x4 acc[4][4]) {
#pragma unroll
  for (int g = 0; g < 4; g++)
#pragma unroll
    for (int rt = 0; rt < 4; rt++)
      acc[g][rt] = mfma_bf16(a[rt], b[g], acc[g][rt]);
}
template <int N>
__device__ __forceinline__ void kloop(const u32x4*& ap, const u32x4*& wp,
                                      f32x4 acc[4][4]) {
  u32x4 a0[4], b0[4], a1[4], b1[4];
  ld4(a0, ap); ld4(b0, wp); ap += 256; wp += 256;
#pragma unroll 1
  for (int i = 0; i < (N - 1) / 2; i++) {
    ld4(a1, ap); ld4(b1, wp); ap += 256; wp += 256;
    mfma16(a0, b0, acc);
    ld4(a0, ap); ld4(b0, wp); ap += 256; wp += 256;
    mfma16(a1, b1, acc);
  }
  if constexpr ((N & 1) == 0) {
    ld4(a1, ap); ld4(b1, wp); ap += 256; wp += 256;
    mfma16(a0, b0, acc);
    mfma16(a1, b1, acc);
  } else {
    mfma16(a0, b0, acc);
  }
}

// ---------------- fused 2-layer LSTM + FC ----------------
// 256 blocks x 512 threads; block owns 64 batch rows for all 10 steps.
// LDS 158 KB (1 blk/CU, 2 waves/SIMD): x-tile + double-buffered h1/h2 in
// bf16 A-layout [kblk][row][8k] + biases; 3 barriers/step.
// K-loops rolled; jt loop unrolled (static c indices -> AGPR residence).
__global__ __attribute__((amdgpu_flat_work_group_size(NTHREADS, NTHREADS),
                          amdgpu_waves_per_eu(2, 2)))
void lstm_fused(const float* __restrict__ x,
                const unsigned short* __restrict__ W0p,
                const unsigned short* __restrict__ W1p,
                const float* __restrict__ b0,
                const float* __restrict__ b1,
                const float* __restrict__ Wfc,
                const float* __restrict__ bfc,
                float* __restrict__ out) {
  __shared__ unsigned int lds_x[20 * 64 * 4];   // 20480 B
  __shared__ unsigned int lds_h1[16384];        // 65536 B = 2 bufs x [32 kblk][64 row][8k]
  __shared__ unsigned int lds_h2[16384];        // 65536 B
  __shared__ float lds_red[512];                // 2048 B
  __shared__ float lds_b0[1024];                // 4096 B
  __shared__ float lds_b1[1024];                // 4096 B   total 161792 B

  const int tid = threadIdx.x;
  const int wave = tid >> 6;
  const int lane = tid & 63;
  const int l15 = lane & 15;
  const int quad = lane >> 4;
  const long rowg0 = (long)blockIdx.x * 64;

  for (int i = tid; i < 16384; i += NTHREADS) { lds_h1[i] = 0u; lds_h2[i] = 0u; }
  for (int i = tid; i < 1024; i += NTHREADS) { lds_b0[i] = b0[i]; lds_b1[i] = b1[i]; }

  // persistent c-state pinned to AGPRs (static indices only!)
  float c0a[2][4][4], c2a[2][4][4];
#pragma unroll
  for (int jt = 0; jt < 2; jt++)
#pragma unroll
    for (int rt = 0; rt < 4; rt++)
#pragma unroll
      for (int r = 0; r < 4; r++) {
        c0a[jt][rt][r] = agpr_st(0.f);
        c2a[jt][rt][r] = agpr_st(0.f);
      }
  float fc_acc = 0.0f;

  const u32x4* lxs = (const u32x4*)lds_x;
  const u32x4* lh1 = (const u32x4*)lds_h1;
  const u32x4* lh2 = (const u32x4*)lds_h2;
  unsigned short* lh1s = (unsigned short*)lds_h1;
  unsigned short* lh2s = (unsigned short*)lds_h2;
  const u32x4* w0q = (const u32x4*)W0p;
  const u32x4* w1q = (const u32x4*)W1p;

  for (int t = 0; t < 10; t++) {
    const int rd = t & 1;        // prev-h buffer
    const int wr = rd ^ 1;       // new-h buffer

    // ---- stage x_t -> lds_x (bf16 A-layout) ----
#pragma unroll
    for (int s = 0; s < 5; s++) {
      int p = tid + s * NTHREADS;          // 2560 f32x4 = 64 rows x 40 quads
      int row = p / 40;
      int kq = p - row * 40;
      const f32x4 v = __builtin_nontemporal_load(
          (const f32x4*)(x + (rowg0 + row) * 1600 + t * 160 + kq * 4));
      unsigned lo = (unsigned)f2bf(v[0]) | ((unsigned)f2bf(v[1]) << 16);
      unsigned hi = (unsigned)f2bf(v[2]) | ((unsigned)f2bf(v[3]) << 16);
      int base = (kq >> 1) * 256 + row * 4 + (kq & 1) * 2;
      lds_x[base] = lo;
      lds_x[base + 1] = hi;
    }
    __syncthreads();  // B1: x staged; h1[rd] stable from prev step

    // ======== layer 0: K=416 ([x_t | h1_prev]) ========
#pragma unroll
    for (int jt = 0; jt < 2; jt++) {
      const int nbb = wave * 2 + jt;
      f32x4 acc[4][4];
#pragma unroll
      for (int g = 0; g < 4; g++)
#pragma unroll
        for (int rt = 0; rt < 4; rt++) acc[g][rt] = (f32x4){0.f, 0.f, 0.f, 0.f};

      const u32x4* wp = w0q + (nbb * 52 + quad) * 64 + l15;
      const u32x4* ap = lxs + quad * 64 + l15;
      kloop<5>(ap, wp, acc);                       // x-part: k 0..159
      ap = lh1 + rd * 2048 + quad * 64 + l15;
      kloop<8>(ap, wp, acc);                       // h-part: k 160..415

      float b_i = lds_b0[0 * 256 + wave * 32 + jt * 16 + l15];
      float b_f = lds_b0[1 * 256 + wave * 32 + jt * 16 + l15];
      float b_g = lds_b0[2 * 256 + wave * 32 + jt * 16 + l15];
      float b_o = lds_b0[3 * 256 + wave * 32 + jt * 16 + l15];
#pragma unroll
      for (int rt = 0; rt < 4; rt++)
#pragma unroll
        for (int r = 0; r < 4; r++) {
          float iv = sigm(acc[0][rt][r] + b_i);
          float fv = sigm(acc[1][rt][r] + b_f);
          float gv = tanh_fast(acc[2][rt][r] + b_g);
          float ov = sigm(acc[3][rt][r] + b_o);
          float cn = fv * agpr_ld(c0a[jt][rt][r]) + iv * gv;
          c0a[jt][rt][r] = agpr_st(cn);
          int row = rt * 16 + quad * 4 + r;
          int col = wave * 32 + jt * 16 + l15;
          lh1s[wr * 16384 + ((col >> 3) * 64 + row) * 8 + (col & 7)] =
              f2bf(ov * tanh_fast(cn));
        }
    }
    __syncthreads();  // B2: h1[wr] complete

    // ======== layer 1: K=512 ([h1_new | h2_prev]) ========
#pragma unroll
    for (int jt = 0; jt < 2; jt++) {
      const int nbb = wave * 2 + jt;
      f32x4 acc[4][4];
#pragma unroll
      for (int g = 0; g < 4; g++)
#pragma unroll
        for (int rt = 0; rt < 4; rt++) acc[g][rt] = (f32x4){0.f, 0.f, 0.f, 0.f};

      const u32x4* wp = w1q + (nbb * 64 + quad) * 64 + l15;
      const u32x4* ap = lh1 + wr * 2048 + quad * 64 + l15;
      kloop<8>(ap, wp, acc);                       // h1_new part: k 0..255
      ap = lh2 + rd * 2048 + quad * 64 + l15;
      kloop<8>(ap, wp, acc);                       // h2_prev part: k 256..511

      float b_i = lds_b1[0 * 256 + wave * 32 + jt * 16 + l15];
      float b_f = lds_b1[1 * 256 + wave * 32 + jt * 16 + l15];
      float b_g = lds_b1[2 * 256 + wave * 32 + jt * 16 + l15];
      float b_o = lds_b1[3 * 256 + wave * 32 + jt * 16 + l15];
#pragma unroll
      for (int rt = 0; rt < 4; rt++)
#pragma unroll
        for (int r = 0; r < 4; r++) {
          float iv = sigm(acc[0][rt][r] + b_i);
          float fv = sigm(acc[1][rt][r] + b_f);
          float gv = tanh_fast(acc[2][rt][r] + b_g);
          float ov = sigm(acc[3][rt][r] + b_o);
          float cn = fv * agpr_ld(c2a[jt][rt][r]) + iv * gv;
          c2a[jt][rt][r] = agpr_st(cn);
          int row = rt * 16 + quad * 4 + r;
          int col = wave * 32 + jt * 16 + l15;
          lh2s[wr * 16384 + ((col >> 3) * 64 + row) * 8 + (col & 7)] =
              f2bf(ov * tanh_fast(cn));
        }
    }
    __syncthreads();  // B3: h2[wr] complete

    // ---- FC partial: logit += W_fc[t*256 + j] * h2_new[row][j] ----
    {
      int row = tid >> 3;
      int jq = (tid & 7) * 32;
      float s = 0.f;
#pragma unroll
      for (int kb = 0; kb < 4; kb++) {
        u32x4 hv = lh2[wr * 2048 + ((jq >> 3) + kb) * 64 + row];
        const f32x4 wA = *(const f32x4*)(Wfc + t * 256 + jq + kb * 8);
        const f32x4 wB = *(const f32x4*)(Wfc + t * 256 + jq + kb * 8 + 4);
#pragma unroll
        for (int e = 0; e < 2; e++) {
          unsigned u = hv[e];
          s += bf2f((unsigned short)(u & 0xffffu)) * wA[2 * e];
          s += bf2f((unsigned short)(u >> 16)) * wA[2 * e + 1];
        }
#pragma unroll
        for (int e = 0; e < 2; e++) {
          unsigned u = hv[2 + e];
          s += bf2f((unsigned short)(u & 0xffffu)) * wB[2 * e];
          s += bf2f((unsigned short)(u >> 16)) * wB[2 * e + 1];
        }
      }
      fc_acc += s;
    }
    // no barrier: next staging touches lds_x only; dbuf protects h regions.
  }

  lds_red[tid] = fc_acc;  // [row(64)][slot(8)]
  __syncthreads();
  if (tid < 64) {
    float s = 0.f;
#pragma unroll
    for (int e = 0; e < 8; e++) s += lds_red[tid * 8 + e];
    out[rowg0 + tid] = sigm(s + bfc[0]);
  }
}

extern "C" void kernel_launch(void* const* d_in, const int* in_sizes, int n_in,
                              void* d_out, int out_size, void* d_ws, size_t ws_size,
                              hipStream_t stream) {
  const float* x    = (const float*)d_in[0];
  const float* Wih0 = (const float*)d_in[1];
  const float* Whh0 = (const float*)d_in[2];
  const float* bih0 = (const float*)d_in[3];
  const float* bhh0 = (const float*)d_in[4];
  const float* Wih1 = (const float*)d_in[5];
  const float* Whh1 = (const float*)d_in[6];
  const float* bih1 = (const float*)d_in[7];
  const float* bhh1 = (const float*)d_in[8];
  const float* Wfc  = (const float*)d_in[9];
  const float* bfc  = (const float*)d_in[10];
  float* out = (float*)d_out;

  unsigned short* W0p = (unsigned short*)d_ws;         // 425984 bf16
  unsigned short* W1p = W0p + 16 * 52 * 4 * 128;       // 524288 bf16
  float* b0 = (float*)(W1p + 16 * 64 * 4 * 128);       // 1024 f32
  float* b1 = b0 + 1024;                               // 1024 f32

  const int total = 16 * 52 * 4 * 128 + 16 * 64 * 4 * 128 + 2048;
  pack_weights<<<(total + 255) / 256, 256, 0, stream>>>(
      Wih0, Whh0, bih0, bhh0, Wih1, Whh1, bih1, bhh1, W0p, W1p, b0, b1);
  lstm_fused<<<256, NTHREADS, 0, stream>>>(x, W0p, W1p, b0, b1, Wfc, bfc, out);
}